// Round 1
// baseline (356.523 us; speedup 1.0000x reference)
//
#include <hip/hip_runtime.h>

#define N_  64
#define D_  128
#define L_  3136
#define K_  64
#define G_  7     // pixel groups per image
#define TPB_ 7    // tiles per block
#define TL_ 64    // pixels per tile

// Fused: normalize + logits + softmax + aggregation (partial, atomically combined)
__global__ __launch_bounds__(256, 3)
void vlad_main(const float* __restrict__ x, const float* __restrict__ w,
               float* __restrict__ vacc, float* __restrict__ asum)
{
    __shared__ __align__(16) float xs[D_][TL_];     // 32 KB, [d][p]
    __shared__ float as[TL_][K_ + 1];               // 16.6 KB, a[p][k], pad->conflict-free
    __shared__ float redA[4][TL_];
    __shared__ float redB[4][TL_];

    const int t    = threadIdx.x;
    const int lane = t & 63;
    const int wv   = __builtin_amdgcn_readfirstlane(t >> 6);  // wave id 0..3 (uniform)
    const int n    = blockIdx.x / G_;
    const int g    = blockIdx.x % G_;

    float acc[32];                 // thread owns k=lane, d = wv*32 + j
#pragma unroll
    for (int j = 0; j < 32; ++j) acc[j] = 0.f;
    float asum_r = 0.f;

    const int dload = (t >> 4);        // 0..15
    const int pload = (t & 15) * 4;    // 0..60 step 4

    const float* wrow = w + (size_t)(wv * 16) * D_;  // 16 conv rows per wave (uniform)

    for (int tile = 0; tile < TPB_; ++tile) {
        const int p0 = (g * TPB_ + tile) * TL_;
        __syncthreads();   // S0: previous tile's consumers done
        // ---- load x tile (coalesced float4) ----
#pragma unroll
        for (int i = 0; i < 8; ++i) {
            const int d = i * 16 + dload;
            const float4 v = *reinterpret_cast<const float4*>(
                x + (size_t)(n * D_ + d) * L_ + p0 + pload);
            *reinterpret_cast<float4*>(&xs[d][pload]) = v;
        }
        __syncthreads();   // S1: tile loaded
        // ---- per-pixel sumsq (pixel = lane, d-chunk per wave) ----
        {
            float s = 0.f;
#pragma unroll
            for (int j = 0; j < 32; ++j) {
                const float v = xs[wv * 32 + j][lane];
                s = fmaf(v, v, s);
            }
            redA[wv][lane] = s;
        }
        __syncthreads();   // S2
        {
            const float tot = redA[0][lane] + redA[1][lane] + redA[2][lane] + redA[3][lane];
            const float inv = 1.f / fmaxf(sqrtf(tot), 1e-12f);
#pragma unroll
            for (int j = 0; j < 32; ++j) xs[wv * 32 + j][lane] *= inv;
        }
        __syncthreads();   // S3: xs normalized; redA free
        // ---- logits: pixel = lane, k = wv*16 + kk (w indices wave-uniform -> s_load) ----
        float lg[16];
#pragma unroll
        for (int kk = 0; kk < 16; ++kk) lg[kk] = 0.f;
#pragma unroll 4
        for (int d = 0; d < D_; ++d) {
            const float xv = xs[d][lane];
#pragma unroll
            for (int kk = 0; kk < 16; ++kk)
                lg[kk] = fmaf(xv, wrow[kk * D_ + d], lg[kk]);
        }
        // ---- softmax over K (cross-wave via LDS) ----
        float mx = lg[0];
#pragma unroll
        for (int kk = 1; kk < 16; ++kk) mx = fmaxf(mx, lg[kk]);
        redA[wv][lane] = mx;
        __syncthreads();   // S4
        mx = fmaxf(fmaxf(redA[0][lane], redA[1][lane]),
                   fmaxf(redA[2][lane], redA[3][lane]));
        float se = 0.f;
#pragma unroll
        for (int kk = 0; kk < 16; ++kk) {
            const float e = __expf(lg[kk] - mx);
            lg[kk] = e;
            se += e;
        }
        redB[wv][lane] = se;
        __syncthreads();   // S5
        {
            const float tot = redB[0][lane] + redB[1][lane] + redB[2][lane] + redB[3][lane];
            const float rs = 1.f / tot;
#pragma unroll
            for (int kk = 0; kk < 16; ++kk) as[lane][wv * 16 + kk] = lg[kk] * rs;
        }
        __syncthreads();   // S6: a ready
        // ---- aggregation: thread owns (k = lane, d = wv*32 + j) ----
        for (int p = 0; p < TL_; p += 4) {
            const float a0 = as[p + 0][lane];
            const float a1 = as[p + 1][lane];
            const float a2 = as[p + 2][lane];
            const float a3 = as[p + 3][lane];
            asum_r += (a0 + a1) + (a2 + a3);
#pragma unroll
            for (int j = 0; j < 32; ++j) {
                const float4 xv = *reinterpret_cast<const float4*>(&xs[wv * 32 + j][p]);
                acc[j] = fmaf(a0, xv.x, acc[j]);
                acc[j] = fmaf(a1, xv.y, acc[j]);
                acc[j] = fmaf(a2, xv.z, acc[j]);
                acc[j] = fmaf(a3, xv.w, acc[j]);
            }
        }
    }
    // ---- commit partials (7 blocks per (n,k,d) address, L2-resident) ----
    float* dst = vacc + ((size_t)n * K_ + lane) * D_ + wv * 32;
#pragma unroll
    for (int j = 0; j < 32; ++j) atomicAdd(dst + j, acc[j]);
    if (wv == 0) atomicAdd(asum + n * K_ + lane, asum_r);
}

// Finalize: v = acc - asum*c; intra-normalize over d; global normalize over K*D
__global__ __launch_bounds__(256)
void vlad_fin(const float* __restrict__ vacc, const float* __restrict__ asum,
              const float* __restrict__ cent, float* __restrict__ out)
{
    __shared__ float sred[4];
    const int t = threadIdx.x;
    const int n = blockIdx.x;
    const int k = t >> 2;      // 0..63
    const int q = t & 3;       // d-chunk 0..3

    const float a = asum[n * K_ + k];
    const float* src = vacc + ((size_t)n * K_ + k) * D_ + q * 32;
    const float* cc  = cent + (size_t)k * D_ + q * 32;

    float v[32];
    float ss = 0.f;
#pragma unroll
    for (int j = 0; j < 32; ++j) {
        const float val = src[j] - a * cc[j];
        v[j] = val;
        ss = fmaf(val, val, ss);
    }
    // reduce over the 4-lane group covering one k-row
    ss += __shfl_xor(ss, 1);
    ss += __shfl_xor(ss, 2);
    const float inv1 = 1.f / fmaxf(sqrtf(ss), 1e-12f);
    float gs = 0.f;
#pragma unroll
    for (int j = 0; j < 32; ++j) { v[j] *= inv1; gs = fmaf(v[j], v[j], gs); }
    // block-wide sum for global norm
#pragma unroll
    for (int off = 1; off < 64; off <<= 1) gs += __shfl_xor(gs, off);
    const int wv = t >> 6;
    if ((t & 63) == 0) sred[wv] = gs;
    __syncthreads();
    const float tot = sred[0] + sred[1] + sred[2] + sred[3];
    const float inv2 = 1.f / fmaxf(sqrtf(tot), 1e-12f);
    float* dst = out + (size_t)n * (K_ * D_) + (size_t)k * D_ + q * 32;
#pragma unroll
    for (int j = 0; j < 32; ++j) dst[j] = v[j] * inv2;
}

extern "C" void kernel_launch(void* const* d_in, const int* in_sizes, int n_in,
                              void* d_out, int out_size, void* d_ws, size_t ws_size,
                              hipStream_t stream)
{
    const float* x = (const float*)d_in[0];   // [N, D, H, W]
    const float* w = (const float*)d_in[1];   // [K, D]
    const float* c = (const float*)d_in[2];   // [K, D]
    float* out  = (float*)d_out;              // [N, K*D]
    float* vacc = (float*)d_ws;                         // N*K*D
    float* asum = vacc + (size_t)N_ * K_ * D_;          // N*K

    const size_t zbytes = ((size_t)N_ * K_ * D_ + (size_t)N_ * K_) * sizeof(float);
    hipMemsetAsync(d_ws, 0, zbytes, stream);

    vlad_main<<<dim3(N_ * G_), dim3(256), 0, stream>>>(x, w, vacc, asum);
    vlad_fin<<<dim3(N_), dim3(256), 0, stream>>>(vacc, asum, c, out);
}